// Round 9
// baseline (7206.194 us; speedup 1.0000x reference)
//
#include <hip/hip_runtime.h>
#include <hip/hip_bf16.h>
#include <math.h>

// Problem constants
constexpr int B = 64, T = 128, D = 512, L = 9, S = 64;
constexpr int G = 4 * D;      // 2048 gate rows per layer
constexpr int NBLK = L * 32;  // 288 persistent blocks

typedef __attribute__((ext_vector_type(8))) short short8;          // 8 bf16 = 4 VGPR
typedef __attribute__((ext_vector_type(8))) unsigned short ushort8;
typedef __attribute__((ext_vector_type(4))) float f32x4;

// ---------------------------------------------------------------------------
// Workspace layout (bytes):
//  Wpk  [L][2048][1024] bf16  rows remapped rr=4*d+gate; k<512=W_ih, k>=512=W_hh
//  bpk  [L][2048] f32         same row remap
//  hemb [T][B][D] bf16
//  hbuf [L][2][B][D] bf16     parity ping-pong h state per layer (MALL-coherent)
//  hfin [T][B][D] f32         layer-8 h history (feeds LayerNorm)
//  cnt  [1] u32               grid barrier ticket counter
// ---------------------------------------------------------------------------
constexpr size_t WPK_BYTES  = (size_t)L * 2048 * 1024 * 2;   // 37,748,736
constexpr size_t BPK_BYTES  = (size_t)L * 2048 * 4;          // 73,728
constexpr size_t HEMB_BYTES = (size_t)T * B * D * 2;         // 8,388,608
constexpr size_t HBUF_BYTES = (size_t)L * 2 * B * D * 2;     // 1,179,648
constexpr size_t HFIN_BYTES = (size_t)T * B * D * 4;         // 16,777,216

// ---------------------------------------------------------------------------
// K0: pack weights+bias to bf16, fused [ih|hh] K-space, remapped rows.
// ---------------------------------------------------------------------------
__global__ __launch_bounds__(256) void k_pack(const float* __restrict__ W_ih,
                                              const float* __restrict__ W_hh,
                                              const float* __restrict__ bsrc,
                                              unsigned short* __restrict__ Wpk,
                                              float* __restrict__ bpk) {
    int rr = blockIdx.x;
    int l  = rr >> 11;
    int rl = rr & 2047;
    int g  = rl & 3, dd = rl >> 2;
    int srow = g * D + dd;  // source row within layer (gate-major)
    int k = threadIdx.x * 4;
    const float* src = (k < D) ? (W_ih + ((size_t)l * G + srow) * D + k)
                               : (W_hh + ((size_t)l * G + srow) * D + (k - D));
    float4 v = *(const float4*)src;
    __hip_bfloat16 b0 = __float2bfloat16(v.x), b1 = __float2bfloat16(v.y),
                   b2 = __float2bfloat16(v.z), b3 = __float2bfloat16(v.w);
    ushort4 pk;
    pk.x = *(unsigned short*)&b0; pk.y = *(unsigned short*)&b1;
    pk.z = *(unsigned short*)&b2; pk.w = *(unsigned short*)&b3;
    *(ushort4*)(Wpk + ((size_t)l * 2048 + rl) * 1024 + k) = pk;
    if (threadIdx.x == 0) bpk[(size_t)l * 2048 + rl] = bsrc[(size_t)l * G + srow];
}

// ---------------------------------------------------------------------------
// K1a: zero the grid-barrier counter (each call: deterministic across replays)
// ---------------------------------------------------------------------------
__global__ void k_zero(unsigned* __restrict__ cnt) { *cnt = 0u; }

// ---------------------------------------------------------------------------
// K1: embedding gather -> hemb [t][b][d] bf16.
// ---------------------------------------------------------------------------
__global__ __launch_bounds__(256) void k_embed(const int* __restrict__ x,
                                               const float* __restrict__ emb,
                                               unsigned short* __restrict__ hemb) {
    int row = blockIdx.x * 2 + (threadIdx.x >> 7);  // row = t*B + b
    int t = row >> 6, b = row & 63;
    int d0 = (threadIdx.x & 127) * 4;
    int xi = x[b * T + t];
    float4 v = *(const float4*)(emb + (size_t)xi * D + d0);
    __hip_bfloat16 b0 = __float2bfloat16(v.x), b1 = __float2bfloat16(v.y),
                   b2 = __float2bfloat16(v.z), b3 = __float2bfloat16(v.w);
    ushort4 pk;
    pk.x = *(unsigned short*)&b0; pk.y = *(unsigned short*)&b1;
    pk.z = *(unsigned short*)&b2; pk.w = *(unsigned short*)&b3;
    *(ushort4*)(hemb + (size_t)row * D + d0) = pk;
}

// ---------------------------------------------------------------------------
// K2: persistent scan kernel.
// Grid = 288 one-wave blocks, pinned to (l = bid>>5, bt = bid&31); output
// tile = 64 batches x 64 wrows.  Diagonals separated by a ticket barrier of
// relaxed system-scope atomics only (no fences -> no cache invalidation).
//
// Operand placement (the round-9 fix):
//  - W_ih slice (64 KB, k<512): staged ONCE into LDS via global_load_lds with
//    source-side XOR swizzle (rule #21); read as conflict-free ds_read_b128.
//    Immune to L2 capacity pressure; reused by all 128 timesteps.
//  - W_hh slice (64 KB, k>=512): global cached loads. 36 blocks/XCD x 64 KB
//    = 2.25 MB < 4 MiB L2 -> resident; 2-deep consume-then-issue reg ring.
//  - h: relaxed system-scope b64 atomic loads (MALL), 4-deep reg ring
//    (~3 steps = 600 cy lookahead >= MALL latency).
// acc[rt][wc] regs = gates i,f,g,o of cell (dd=bt*16+wc*4+fq, bb=rt*16+fr);
// c state lives in registers for the whole 128-step sequence.
// ---------------------------------------------------------------------------
struct HF { short8 f[2][4]; };  // [kc][rt]
struct WF { short8 f[2][4]; };  // [kc][wc]

__device__ __forceinline__ HF load_h(const unsigned short* hb,
                                     const unsigned short* hp,
                                     int s, int fr, int fq) {
    HF r;
    const int k0 = s * 64;
    const unsigned short* hx = (k0 < D) ? hb : hp;
    const int kk = (k0 & (D - 1)) + fq * 8;
#pragma unroll
    for (int kc = 0; kc < 2; kc++)
#pragma unroll
        for (int rt = 0; rt < 4; rt++) {
            unsigned long long* p = (unsigned long long*)(hx +
                (size_t)(rt * 16 + fr) * D + kk + kc * 32);
            union { unsigned long long u[2]; short8 v; } tmp;
            tmp.u[0] = __hip_atomic_load(p, __ATOMIC_RELAXED, __HIP_MEMORY_SCOPE_SYSTEM);
            tmp.u[1] = __hip_atomic_load(p + 1, __ATOMIC_RELAXED, __HIP_MEMORY_SCOPE_SYSTEM);
            r.f[kc][rt] = tmp.v;
        }
    return r;
}

__device__ __forceinline__ WF load_whh(const unsigned short* wbase,
                                       int s, int fr, int fq) {
    WF r;
    const int k0 = s * 64;  // s>=8 -> elems [512,1024) = hh half
#pragma unroll
    for (int kc = 0; kc < 2; kc++)
#pragma unroll
        for (int wc = 0; wc < 4; wc++)
            r.f[kc][wc] = *(const short8*)(wbase + (size_t)(wc * 16 + fr) * 1024 +
                                           k0 + kc * 32 + fq * 8);
    return r;
}

__device__ __forceinline__ void compute_hh(f32x4 acc[4][4], const WF& w, const HF& h) {
#pragma unroll
    for (int kc = 0; kc < 2; kc++)
#pragma unroll
        for (int wc = 0; wc < 4; wc++)
#pragma unroll
            for (int rt = 0; rt < 4; rt++)
                acc[rt][wc] = __builtin_amdgcn_mfma_f32_16x16x32_bf16(
                    w.f[kc][wc], h.f[kc][rt], acc[rt][wc], 0, 0, 0);
}

__global__ __launch_bounds__(64, 1) void k_scan(const unsigned short* __restrict__ Wpk,
                                                const float* __restrict__ bpk,
                                                const unsigned short* __restrict__ hemb,
                                                unsigned short* __restrict__ hbuf,
                                                float* __restrict__ hfin,
                                                unsigned* __restrict__ cnt) {
    const int bid = blockIdx.x;
    const int l   = bid >> 5;   // layer 0..8
    const int bt  = bid & 31;   // row chunk
    const int lane = threadIdx.x;
    const int fr = lane & 15, fq = lane >> 4;

    const unsigned short* wbase = Wpk + ((size_t)l * 2048 + (size_t)bt * 64) * 1024;

    __shared__ unsigned short Wlds[64][512];  // W_ih slice, swizzled (64 KB)
    __shared__ unsigned short hst[64][16];    // bf16 h staging for coalesced store
    __shared__ float fst[64][16];             // f32 staging for hfin (l==8)

    // ---- Stage W_ih (k<512) into LDS once; source pre-swizzled (rule #21).
    // One row (64 chunks of 16B) per issue; lane = dest chunk; source chunk =
    // lane ^ (row & 7).  Read side XORs the same way -> conflict-free b128.
#pragma unroll 4
    for (int r = 0; r < 64; ++r) {
        const unsigned short* src = wbase + (size_t)r * 1024 + ((lane ^ (r & 7)) << 3);
        __builtin_amdgcn_global_load_lds(
            (const __attribute__((address_space(1))) unsigned int*)src,
            (__attribute__((address_space(3))) unsigned int*)&Wlds[r][0],
            16, 0, 0);
    }
    asm volatile("s_waitcnt vmcnt(0)" ::: "memory");
    __syncthreads();

    // bias: dd = bt*16 + wc*4 + fq, 4 gates each (constant per block+lane)
    float4 bias4[4];
#pragma unroll
    for (int wc = 0; wc < 4; wc++)
        bias4[wc] = *(const float4*)(bpk + (size_t)l * 2048 + ((bt * 16 + wc * 4 + fq) << 2));

    float c_reg[4][4];
#pragma unroll
    for (int i = 0; i < 4; i++)
#pragma unroll
        for (int j = 0; j < 4; j++) c_reg[i][j] = 0.f;

    for (int d = 0; d < L + T - 1; ++d) {
        const int t = d - l;
        if (t >= 0 && t < T) {
            const unsigned short* hb = (l == 0)
                ? (hemb + (size_t)t * B * D)
                : (hbuf + ((size_t)(l - 1) * 2 + (t & 1)) * B * D);
            const unsigned short* hp = hbuf + ((size_t)l * 2 + ((t - 1) & 1)) * B * D;

            f32x4 acc[4][4];
#pragma unroll
            for (int i = 0; i < 4; i++)
#pragma unroll
                for (int j = 0; j < 4; j++) acc[i][j] = f32x4{0.f, 0.f, 0.f, 0.f};

            const int NS = (t > 0) ? 16 : 8;
            HF h[4];
            WF w[2];
            h[0] = load_h(hb, hp, 0, fr, fq);
            h[1] = load_h(hb, hp, 1, fr, fq);
            h[2] = load_h(hb, hp, 2, fr, fq);

#pragma unroll
            for (int s = 0; s < 16; ++s) {
                if (s >= NS) break;
                if (s + 3 < NS) h[(s + 3) & 3] = load_h(hb, hp, s + 3, fr, fq);
                __builtin_amdgcn_sched_barrier(0);
                if (s < 8) {
                    // W from LDS (swizzled read)
#pragma unroll
                    for (int kc = 0; kc < 2; kc++) {
#pragma unroll
                        for (int wc = 0; wc < 4; wc++) {
                            const int chunk = s * 8 + kc * 4 + fq;
                            short8 wf = *(const short8*)&Wlds[wc * 16 + fr]
                                                             [(chunk ^ (fr & 7)) << 3];
#pragma unroll
                            for (int rt = 0; rt < 4; rt++)
                                acc[rt][wc] = __builtin_amdgcn_mfma_f32_16x16x32_bf16(
                                    wf, h[s & 3].f[kc][rt], acc[rt][wc], 0, 0, 0);
                        }
                    }
                } else {
                    compute_hh(acc, w[s & 1], h[s & 3]);
                }
                // consume-then-issue W_hh ring (slot free after compute)
                if (s >= 6 && s + 2 >= 8 && s + 2 < NS)
                    w[(s + 2) & 1] = load_whh(wbase, s + 2, fr, fq);
            }

            // Epilogue: acc[rt][wc] = (i,f,g,o) of cell (dd, bb) in-lane.
            unsigned short* hout = hbuf + ((size_t)l * 2 + (t & 1)) * B * D;
#pragma unroll
            for (int rt = 0; rt < 4; rt++) {
#pragma unroll
                for (int wc = 0; wc < 4; wc++) {
                    float gi = acc[rt][wc].x + bias4[wc].x;
                    float gf = acc[rt][wc].y + bias4[wc].y;
                    float gg = acc[rt][wc].z + bias4[wc].z;
                    float go = acc[rt][wc].w + bias4[wc].w;
                    float si = 1.f / (1.f + __expf(-gi));
                    float sf = 1.f / (1.f + __expf(-gf));
                    float so = 1.f / (1.f + __expf(-go));
                    float tg = tanhf(gg);
                    float cn = (t > 0) ? fmaf(sf, c_reg[rt][wc], si * tg) : (si * tg);
                    c_reg[rt][wc] = cn;
                    float hv = so * tanhf(cn);
                    __hip_bfloat16 hvb = __float2bfloat16(hv);
                    hst[rt * 16 + fr][wc * 4 + fq] = *(unsigned short*)&hvb;
                    if (l == 8) fst[rt * 16 + fr][wc * 4 + fq] = hv;
                }
            }
            __syncthreads();
            // Coalesced stores to the coherence point: relaxed system-scope
            // b64 atomic stores (global_store_dwordx2 sc0 sc1; no fence).
            {
                unsigned short* dst = hout + (size_t)lane * D + bt * 16;
#pragma unroll
                for (int j = 0; j < 4; j++) {
                    unsigned long long v = *(const unsigned long long*)&hst[lane][j * 4];
                    __hip_atomic_store((unsigned long long*)(dst + j * 4), v,
                                       __ATOMIC_RELAXED, __HIP_MEMORY_SCOPE_SYSTEM);
                }
            }
            if (l == 8) {
                float* dst = hfin + ((size_t)t * B + lane) * D + bt * 16;
#pragma unroll
                for (int j = 0; j < 4; j++)
                    *(float4*)(dst + j * 4) = *(const float4*)&fst[lane][j * 4];
            }
            __syncthreads();
        }
        // ---- Ticket barrier: relaxed system atomics only (no cache inv) ----
        asm volatile("s_waitcnt vmcnt(0)" ::: "memory");
        if (lane == 0) {
            __hip_atomic_fetch_add(cnt, 1u, __ATOMIC_RELAXED, __HIP_MEMORY_SCOPE_SYSTEM);
            const unsigned tgt = (unsigned)NBLK * (unsigned)(d + 1);
            while (__hip_atomic_load(cnt, __ATOMIC_RELAXED, __HIP_MEMORY_SCOPE_SYSTEM) < tgt)
                __builtin_amdgcn_s_sleep(2);
        }
        __syncthreads();
        __builtin_amdgcn_sched_barrier(0);
        asm volatile("" ::: "memory");
    }
}

// ---------------------------------------------------------------------------
// K3: LayerNorm.  hfin [t*B+b][D] f32 -> hn [b*T+t][D] f32.  1 wave per row.
// ---------------------------------------------------------------------------
__global__ __launch_bounds__(256) void k_ln(const float* __restrict__ hfin,
                                            const float* __restrict__ gamma,
                                            const float* __restrict__ beta,
                                            float* __restrict__ hn) {
    int row  = blockIdx.x * 4 + (threadIdx.x >> 6);  // t*B + b
    int lane = threadIdx.x & 63;
    int t = row >> 6, b = row & 63;
    const float* in = hfin + (size_t)row * D;
    float4 a = *((const float4*)in + lane * 2);
    float4 c = *((const float4*)in + lane * 2 + 1);
    float s1 = a.x + a.y + a.z + a.w + c.x + c.y + c.z + c.w;
    float s2 = a.x * a.x + a.y * a.y + a.z * a.z + a.w * a.w +
               c.x * c.x + c.y * c.y + c.z * c.z + c.w * c.w;
#pragma unroll
    for (int m = 1; m < 64; m <<= 1) {
        s1 += __shfl_xor(s1, m);
        s2 += __shfl_xor(s2, m);
    }
    float mean = s1 / D;
    float rstd = rsqrtf(s2 / D - mean * mean + 1e-5f);
    float4 g0 = *((const float4*)gamma + lane * 2);
    float4 g1 = *((const float4*)gamma + lane * 2 + 1);
    float4 be0 = *((const float4*)beta + lane * 2);
    float4 be1 = *((const float4*)beta + lane * 2 + 1);
    float4 o0, o1;
    o0.x = fmaf((a.x - mean) * rstd, g0.x, be0.x);
    o0.y = fmaf((a.y - mean) * rstd, g0.y, be0.y);
    o0.z = fmaf((a.z - mean) * rstd, g0.z, be0.z);
    o0.w = fmaf((a.w - mean) * rstd, g0.w, be0.w);
    o1.x = fmaf((c.x - mean) * rstd, g1.x, be1.x);
    o1.y = fmaf((c.y - mean) * rstd, g1.y, be1.y);
    o1.z = fmaf((c.z - mean) * rstd, g1.z, be1.z);
    o1.w = fmaf((c.w - mean) * rstd, g1.w, be1.w);
    float* out = hn + ((size_t)b * T + t) * D;
    *((float4*)out + lane * 2) = o0;
    *((float4*)out + lane * 2 + 1) = o1;
}

// ---------------------------------------------------------------------------
// K4: head GEMM  logits[m][s] = sum_k hn[m][k]*head_W[s][k] + head_b[s]
// ---------------------------------------------------------------------------
__global__ __launch_bounds__(256) void k_head(const float* __restrict__ hn,
                                              const float* __restrict__ hw,
                                              const float* __restrict__ hb,
                                              float* __restrict__ out) {
    int m0 = blockIdx.x * 64;
    int tid = threadIdx.x;
    int tx = tid & 15, ty = tid >> 4;

    __shared__ float As[32][68];
    __shared__ float Bs[32][68];
    float acc[4][4] = {};

    for (int k0 = 0; k0 < D; k0 += 32) {
        int mm = tid >> 3, f4k = tid & 7;
#pragma unroll
        for (int h2 = 0; h2 < 2; h2++) {
            int m = mm + h2 * 32;
            float4 a = *((const float4*)(hn + (size_t)(m0 + m) * D + k0) + f4k);
            As[f4k * 4 + 0][m] = a.x;
            As[f4k * 4 + 1][m] = a.y;
            As[f4k * 4 + 2][m] = a.z;
            As[f4k * 4 + 3][m] = a.w;
            float4 wv = *((const float4*)(hw + (size_t)m * D + k0) + f4k);
            Bs[f4k * 4 + 0][m] = wv.x;
            Bs[f4k * 4 + 1][m] = wv.y;
            Bs[f4k * 4 + 2][m] = wv.z;
            Bs[f4k * 4 + 3][m] = wv.w;
        }
        __syncthreads();
#pragma unroll
        for (int k = 0; k < 32; k++) {
            float4 a  = *(float4*)&As[k][ty * 4];
            float4 bb = *(float4*)&Bs[k][tx * 4];
            float av[4] = {a.x, a.y, a.z, a.w};
            float bv[4] = {bb.x, bb.y, bb.z, bb.w};
#pragma unroll
            for (int i = 0; i < 4; i++)
#pragma unroll
                for (int j = 0; j < 4; j++) acc[i][j] = fmaf(av[i], bv[j], acc[i][j]);
        }
        __syncthreads();
    }
    float* o = out + (size_t)m0 * S;
#pragma unroll
    for (int i = 0; i < 4; i++) {
        int m = ty * 4 + i;
        float4 v;
        v.x = acc[i][0] + hb[tx * 4 + 0];
        v.y = acc[i][1] + hb[tx * 4 + 1];
        v.z = acc[i][2] + hb[tx * 4 + 2];
        v.w = acc[i][3] + hb[tx * 4 + 3];
        *(float4*)(o + (size_t)m * S + tx * 4) = v;
    }
}

// ---------------------------------------------------------------------------
extern "C" void kernel_launch(void* const* d_in, const int* in_sizes, int n_in,
                              void* d_out, int out_size, void* d_ws, size_t ws_size,
                              hipStream_t stream) {
    const int*   x      = (const int*)d_in[0];
    const float* emb    = (const float*)d_in[1];
    const float* W_ih   = (const float*)d_in[2];
    const float* W_hh   = (const float*)d_in[3];
    const float* bvec   = (const float*)d_in[4];
    const float* gamma  = (const float*)d_in[5];
    const float* beta   = (const float*)d_in[6];
    const float* head_W = (const float*)d_in[7];
    const float* head_b = (const float*)d_in[8];

    float* logits = (float*)d_out;                      // [B,T,S]
    float* hn     = (float*)d_out + (size_t)B * T * S;  // [B,T,D]

    char* ws = (char*)d_ws;
    unsigned short* Wpk  = (unsigned short*)ws;
    float*          bpk  = (float*)(ws + WPK_BYTES);
    unsigned short* hemb = (unsigned short*)(ws + WPK_BYTES + BPK_BYTES);
    unsigned short* hbuf = (unsigned short*)(ws + WPK_BYTES + BPK_BYTES + HEMB_BYTES);
    float*          hfin = (float*)(ws + WPK_BYTES + BPK_BYTES + HEMB_BYTES + HBUF_BYTES);
    unsigned*       cnt  = (unsigned*)(ws + WPK_BYTES + BPK_BYTES + HEMB_BYTES + HBUF_BYTES + HFIN_BYTES);

    k_zero<<<dim3(1), 1, 0, stream>>>(cnt);
    k_pack<<<dim3(L * 2048), 256, 0, stream>>>(W_ih, W_hh, bvec, Wpk, bpk);
    k_embed<<<dim3(T * B / 2), 256, 0, stream>>>(x, emb, hemb);

    k_scan<<<dim3(NBLK), dim3(64), 0, stream>>>(Wpk, bpk, hemb, hbuf, hfin, cnt);

    k_ln<<<dim3(B * T / 4), 256, 0, stream>>>(hfin, gamma, beta, hn);
    k_head<<<dim3(B * T / 64), 256, 0, stream>>>(hn, head_W, head_b, logits);
}

// Round 10
// 3138.340 us; speedup vs baseline: 2.2962x; 2.2962x over previous
//
#include <hip/hip_runtime.h>
#include <hip/hip_bf16.h>
#include <math.h>

// Problem constants
constexpr int B = 64, T = 128, D = 512, L = 9, S = 64;
constexpr int G = 4 * D;  // 2048 gate rows per layer

typedef __attribute__((ext_vector_type(8))) short short8;          // 8 bf16 = 4 VGPR
typedef __attribute__((ext_vector_type(8))) unsigned short ushort8;
typedef __attribute__((ext_vector_type(4))) float f32x4;

// ---------------------------------------------------------------------------
// Workspace layout (bytes):
//  Wpk  [L][2048][1024] bf16  rows remapped rr=4*d+gate; k<512=W_ih, k>=512=W_hh
//  bpk  [L][2048] f32         same row remap
//  hemb [T][B][D] bf16
//  hpp  [2][L][B][D] bf16     parity ping-pong h state (incl. layer 8)
//  hfin [T][B][D] f32         layer-8 h history (feeds LayerNorm)
//  cbuf [L*32][16][64] f32    c state, lane-private register-order layout
// ---------------------------------------------------------------------------
constexpr size_t WPK_BYTES  = (size_t)L * 2048 * 1024 * 2;   // 37,748,736
constexpr size_t BPK_BYTES  = (size_t)L * 2048 * 4;          // 73,728
constexpr size_t HEMB_BYTES = (size_t)T * B * D * 2;         // 8,388,608
constexpr size_t HPP_BYTES  = (size_t)2 * L * B * D * 2;     // 1,179,648
constexpr size_t HFIN_BYTES = (size_t)T * B * D * 4;         // 16,777,216

// ---------------------------------------------------------------------------
// K0: pack weights+bias to bf16, fused [ih|hh] K-space, remapped rows.
// ---------------------------------------------------------------------------
__global__ __launch_bounds__(256) void k_pack(const float* __restrict__ W_ih,
                                              const float* __restrict__ W_hh,
                                              const float* __restrict__ bsrc,
                                              unsigned short* __restrict__ Wpk,
                                              float* __restrict__ bpk) {
    int rr = blockIdx.x;
    int l  = rr >> 11;
    int rl = rr & 2047;
    int g  = rl & 3, dd = rl >> 2;
    int srow = g * D + dd;  // source row within layer (gate-major)
    int k = threadIdx.x * 4;
    const float* src = (k < D) ? (W_ih + ((size_t)l * G + srow) * D + k)
                               : (W_hh + ((size_t)l * G + srow) * D + (k - D));
    float4 v = *(const float4*)src;
    __hip_bfloat16 b0 = __float2bfloat16(v.x), b1 = __float2bfloat16(v.y),
                   b2 = __float2bfloat16(v.z), b3 = __float2bfloat16(v.w);
    ushort4 pk;
    pk.x = *(unsigned short*)&b0; pk.y = *(unsigned short*)&b1;
    pk.z = *(unsigned short*)&b2; pk.w = *(unsigned short*)&b3;
    *(ushort4*)(Wpk + ((size_t)l * 2048 + rl) * 1024 + k) = pk;
    if (threadIdx.x == 0) bpk[(size_t)l * 2048 + rl] = bsrc[(size_t)l * G + srow];
}

// ---------------------------------------------------------------------------
// K1: embedding gather -> hemb [t][b][d] bf16.
// ---------------------------------------------------------------------------
__global__ __launch_bounds__(256) void k_embed(const int* __restrict__ x,
                                               const float* __restrict__ emb,
                                               unsigned short* __restrict__ hemb) {
    int row = blockIdx.x * 2 + (threadIdx.x >> 7);  // row = t*B + b
    int t = row >> 6, b = row & 63;
    int d0 = (threadIdx.x & 127) * 4;
    int xi = x[b * T + t];
    float4 v = *(const float4*)(emb + (size_t)xi * D + d0);
    __hip_bfloat16 b0 = __float2bfloat16(v.x), b1 = __float2bfloat16(v.y),
                   b2 = __float2bfloat16(v.z), b3 = __float2bfloat16(v.w);
    ushort4 pk;
    pk.x = *(unsigned short*)&b0; pk.y = *(unsigned short*)&b1;
    pk.z = *(unsigned short*)&b2; pk.w = *(unsigned short*)&b3;
    *(ushort4*)(hemb + (size_t)row * D + d0) = pk;
}

// ---------------------------------------------------------------------------
// K2: one wavefront-diagonal of LSTM cells — register-tile MFMA version.
// One launch per diagonal d (= l + t); grid = ncells*32 one-wave blocks.
// Block = (cell ci, bt): output tile = 64 batches x 64 wrows.
// Main loop: NO LDS. 2-deep register ring of W/h fragments via normal cached
// global loads (L2/L3-warm across launches; kernel boundary = coherence).
// MFMA operand order (A=wf, B=hf) => acc[rt][wc].xyzw = gates i,f,g,o of
// cell (dd = bt*16+wc*4+fq, bb = rt*16+fr) -- no cross-lane transpose.
// c state in global, lane-private register-order layout (coalesced).
// State ping-pong by diagonal parity: reads parity p^1, writes parity p.
// ---------------------------------------------------------------------------
struct Frags {
    short8 h[2][4];  // [kc][rt]
    short8 w[2][4];  // [kc][wc]
};

__device__ __forceinline__ Frags load_step(const unsigned short* __restrict__ hb,
                                           const unsigned short* __restrict__ hp,
                                           const unsigned short* __restrict__ wbase,
                                           int k0, int fr, int fq) {
    Frags f;
    const unsigned short* hx = (k0 < D) ? hb : hp;
    const int kk = (k0 & (D - 1)) + fq * 8;
#pragma unroll
    for (int kc = 0; kc < 2; kc++) {
#pragma unroll
        for (int rt = 0; rt < 4; rt++)
            f.h[kc][rt] = *(const short8*)(hx + (size_t)(rt * 16 + fr) * D + kk + kc * 32);
#pragma unroll
        for (int wc = 0; wc < 4; wc++)
            f.w[kc][wc] = *(const short8*)(wbase + (size_t)(wc * 16 + fr) * 1024 +
                                           k0 + kc * 32 + fq * 8);
    }
    return f;
}

__device__ __forceinline__ void compute_step(f32x4 acc[4][4], const Frags& f) {
#pragma unroll
    for (int kc = 0; kc < 2; kc++)
#pragma unroll
        for (int wc = 0; wc < 4; wc++)
#pragma unroll
            for (int rt = 0; rt < 4; rt++)
                acc[rt][wc] = __builtin_amdgcn_mfma_f32_16x16x32_bf16(
                    f.w[kc][wc], f.h[kc][rt], acc[rt][wc], 0, 0, 0);
}

template <int NS>
__device__ __forceinline__ void gemm_pipe(f32x4 acc[4][4],
                                          const unsigned short* __restrict__ hb,
                                          const unsigned short* __restrict__ hp,
                                          const unsigned short* __restrict__ wbase,
                                          int fr, int fq) {
    Frags cur = load_step(hb, hp, wbase, 0, fr, fq);
#pragma unroll 2
    for (int s = 0; s < NS - 1; ++s) {
        Frags nxt = load_step(hb, hp, wbase, (s + 1) * 64, fr, fq);
        __builtin_amdgcn_sched_barrier(0);
        compute_step(acc, cur);
        cur = nxt;
    }
    compute_step(acc, cur);
}

__global__ __launch_bounds__(64) void k_cell(const unsigned short* __restrict__ Wpk,
                                             const float* __restrict__ bpk,
                                             const unsigned short* __restrict__ hemb,
                                             unsigned short* __restrict__ hpp,
                                             float* __restrict__ cbuf,
                                             float* __restrict__ hfin,
                                             int d) {
    const int lmin = (d > T - 1) ? (d - (T - 1)) : 0;
    const int l  = lmin + (blockIdx.x >> 5);
    const int bt = blockIdx.x & 31;
    const int t  = d - l;
    const int p  = d & 1;

    const int lane = threadIdx.x;
    const int fr = lane & 15, fq = lane >> 4;

    const unsigned short* wbase = Wpk + ((size_t)l * 2048 + (size_t)bt * 64) * 1024;

    const unsigned short* hb = (l == 0)
        ? (hemb + (size_t)t * B * D)
        : (hpp + ((size_t)(p ^ 1) * L + (l - 1)) * B * D);
    const unsigned short* hp = hpp + ((size_t)(p ^ 1) * L + l) * B * D;
    unsigned short* hout = hpp + ((size_t)p * L + l) * B * D;

    // bias: dd = bt*16 + wc*4 + fq -> rows 4*dd..4*dd+3 (i,f,g,o)
    float4 bias4[4];
#pragma unroll
    for (int wc = 0; wc < 4; wc++)
        bias4[wc] = *(const float4*)(bpk + (size_t)l * 2048 + ((bt * 16 + wc * 4 + fq) << 2));

    f32x4 acc[4][4];
#pragma unroll
    for (int i = 0; i < 4; i++)
#pragma unroll
        for (int j = 0; j < 4; j++) acc[i][j] = f32x4{0.f, 0.f, 0.f, 0.f};

    if (t > 0) gemm_pipe<16>(acc, hb, hp, wbase, fr, fq);
    else       gemm_pipe<8>(acc, hb, hp, wbase, fr, fq);

    __shared__ unsigned short hst[64][16];  // [batch][dd_local] bf16
    __shared__ float fst[64][16];           // f32 for hfin (l==8)

    // c: lane-private layout cbuf[(l*32+bt)*16 + rt*4+wc][lane]
    float* cb = cbuf + ((size_t)(l * 32 + bt) * 16) * 64 + lane;

#pragma unroll
    for (int rt = 0; rt < 4; rt++) {
#pragma unroll
        for (int wc = 0; wc < 4; wc++) {
            float gi = acc[rt][wc].x + bias4[wc].x;
            float gf = acc[rt][wc].y + bias4[wc].y;
            float gg = acc[rt][wc].z + bias4[wc].z;
            float go = acc[rt][wc].w + bias4[wc].w;
            float si = 1.f / (1.f + __expf(-gi));
            float sf = 1.f / (1.f + __expf(-gf));
            float so = 1.f / (1.f + __expf(-go));
            float tg = tanhf(gg);
            float co = (t > 0) ? cb[(rt * 4 + wc) * 64] : 0.f;
            float cn = fmaf(sf, co, si * tg);
            cb[(rt * 4 + wc) * 64] = cn;
            float hv = so * tanhf(cn);
            __hip_bfloat16 hvb = __float2bfloat16(hv);
            hst[rt * 16 + fr][wc * 4 + fq] = *(unsigned short*)&hvb;
            if (l == 8) fst[rt * 16 + fr][wc * 4 + fq] = hv;
        }
    }
    __syncthreads();
    // Coalesced store: lane = batch row, 16 dd values = 32 B
    {
        ushort8 r0 = *(const ushort8*)&hst[lane][0];
        ushort8 r1 = *(const ushort8*)&hst[lane][8];
        unsigned short* dst = hout + (size_t)lane * D + bt * 16;
        *(ushort8*)dst = r0;
        *(ushort8*)(dst + 8) = r1;
    }
    if (l == 8) {
        float* dst = hfin + ((size_t)t * B + lane) * D + bt * 16;
#pragma unroll
        for (int j = 0; j < 4; j++)
            *(float4*)(dst + j * 4) = *(const float4*)&fst[lane][j * 4];
    }
}

// ---------------------------------------------------------------------------
// K3: LayerNorm.  hfin [t*B+b][D] f32 -> hn [b*T+t][D] f32.  1 wave per row.
// ---------------------------------------------------------------------------
__global__ __launch_bounds__(256) void k_ln(const float* __restrict__ hfin,
                                            const float* __restrict__ gamma,
                                            const float* __restrict__ beta,
                                            float* __restrict__ hn) {
    int row  = blockIdx.x * 4 + (threadIdx.x >> 6);  // t*B + b
    int lane = threadIdx.x & 63;
    int t = row >> 6, b = row & 63;
    const float* in = hfin + (size_t)row * D;
    float4 a = *((const float4*)in + lane * 2);
    float4 c = *((const float4*)in + lane * 2 + 1);
    float s1 = a.x + a.y + a.z + a.w + c.x + c.y + c.z + c.w;
    float s2 = a.x * a.x + a.y * a.y + a.z * a.z + a.w * a.w +
               c.x * c.x + c.y * c.y + c.z * c.z + c.w * c.w;
#pragma unroll
    for (int m = 1; m < 64; m <<= 1) {
        s1 += __shfl_xor(s1, m);
        s2 += __shfl_xor(s2, m);
    }
    float mean = s1 / D;
    float rstd = rsqrtf(s2 / D - mean * mean + 1e-5f);
    float4 g0 = *((const float4*)gamma + lane * 2);
    float4 g1 = *((const float4*)gamma + lane * 2 + 1);
    float4 be0 = *((const float4*)beta + lane * 2);
    float4 be1 = *((const float4*)beta + lane * 2 + 1);
    float4 o0, o1;
    o0.x = fmaf((a.x - mean) * rstd, g0.x, be0.x);
    o0.y = fmaf((a.y - mean) * rstd, g0.y, be0.y);
    o0.z = fmaf((a.z - mean) * rstd, g0.z, be0.z);
    o0.w = fmaf((a.w - mean) * rstd, g0.w, be0.w);
    o1.x = fmaf((c.x - mean) * rstd, g1.x, be1.x);
    o1.y = fmaf((c.y - mean) * rstd, g1.y, be1.y);
    o1.z = fmaf((c.z - mean) * rstd, g1.z, be1.z);
    o1.w = fmaf((c.w - mean) * rstd, g1.w, be1.w);
    float* out = hn + ((size_t)b * T + t) * D;
    *((float4*)out + lane * 2) = o0;
    *((float4*)out + lane * 2 + 1) = o1;
}

// ---------------------------------------------------------------------------
// K4: head GEMM  logits[m][s] = sum_k hn[m][k]*head_W[s][k] + head_b[s]
// ---------------------------------------------------------------------------
__global__ __launch_bounds__(256) void k_head(const float* __restrict__ hn,
                                              const float* __restrict__ hw,
                                              const float* __restrict__ hb,
                                              float* __restrict__ out) {
    int m0 = blockIdx.x * 64;
    int tid = threadIdx.x;
    int tx = tid & 15, ty = tid >> 4;

    __shared__ float As[32][68];
    __shared__ float Bs[32][68];
    float acc[4][4] = {};

    for (int k0 = 0; k0 < D; k0 += 32) {
        int mm = tid >> 3, f4k = tid & 7;
#pragma unroll
        for (int h2 = 0; h2 < 2; h2++) {
            int m = mm + h2 * 32;
            float4 a = *((const float4*)(hn + (size_t)(m0 + m) * D + k0) + f4k);
            As[f4k * 4 + 0][m] = a.x;
            As[f4k * 4 + 1][m] = a.y;
            As[f4k * 4 + 2][m] = a.z;
            As[f4k * 4 + 3][m] = a.w;
            float4 wv = *((const float4*)(hw + (size_t)m * D + k0) + f4k);
            Bs[f4k * 4 + 0][m] = wv.x;
            Bs[f4k * 4 + 1][m] = wv.y;
            Bs[f4k * 4 + 2][m] = wv.z;
            Bs[f4k * 4 + 3][m] = wv.w;
        }
        __syncthreads();
#pragma unroll
        for (int k = 0; k < 32; k++) {
            float4 a  = *(float4*)&As[k][ty * 4];
            float4 bb = *(float4*)&Bs[k][tx * 4];
            float av[4] = {a.x, a.y, a.z, a.w};
            float bv[4] = {bb.x, bb.y, bb.z, bb.w};
#pragma unroll
            for (int i = 0; i < 4; i++)
#pragma unroll
                for (int j = 0; j < 4; j++) acc[i][j] = fmaf(av[i], bv[j], acc[i][j]);
        }
        __syncthreads();
    }
    float* o = out + (size_t)m0 * S;
#pragma unroll
    for (int i = 0; i < 4; i++) {
        int m = ty * 4 + i;
        float4 v;
        v.x = acc[i][0] + hb[tx * 4 + 0];
        v.y = acc[i][1] + hb[tx * 4 + 1];
        v.z = acc[i][2] + hb[tx * 4 + 2];
        v.w = acc[i][3] + hb[tx * 4 + 3];
        *(float4*)(o + (size_t)m * S + tx * 4) = v;
    }
}

// ---------------------------------------------------------------------------
extern "C" void kernel_launch(void* const* d_in, const int* in_sizes, int n_in,
                              void* d_out, int out_size, void* d_ws, size_t ws_size,
                              hipStream_t stream) {
    const int*   x      = (const int*)d_in[0];
    const float* emb    = (const float*)d_in[1];
    const float* W_ih   = (const float*)d_in[2];
    const float* W_hh   = (const float*)d_in[3];
    const float* bvec   = (const float*)d_in[4];
    const float* gamma  = (const float*)d_in[5];
    const float* beta   = (const float*)d_in[6];
    const float* head_W = (const float*)d_in[7];
    const float* head_b = (const float*)d_in[8];

    float* logits = (float*)d_out;                      // [B,T,S]
    float* hn     = (float*)d_out + (size_t)B * T * S;  // [B,T,D]

    char* ws = (char*)d_ws;
    unsigned short* Wpk  = (unsigned short*)ws;
    float*          bpk  = (float*)(ws + WPK_BYTES);
    unsigned short* hemb = (unsigned short*)(ws + WPK_BYTES + BPK_BYTES);
    unsigned short* hpp  = (unsigned short*)(ws + WPK_BYTES + BPK_BYTES + HEMB_BYTES);
    float*          hfin = (float*)(ws + WPK_BYTES + BPK_BYTES + HEMB_BYTES + HPP_BYTES);
    float*          cbuf = (float*)(ws + WPK_BYTES + BPK_BYTES + HEMB_BYTES + HPP_BYTES + HFIN_BYTES);

    k_pack<<<dim3(L * 2048), 256, 0, stream>>>(W_ih, W_hh, bvec, Wpk, bpk);
    k_embed<<<dim3(T * B / 2), 256, 0, stream>>>(x, emb, hemb);

    for (int d = 0; d < L + T - 1; ++d) {
        int lmin = (d > T - 1) ? (d - (T - 1)) : 0;
        int lmax = (d < L - 1) ? d : (L - 1);
        int ncells = lmax - lmin + 1;
        k_cell<<<dim3(ncells * 32), dim3(64), 0, stream>>>(Wpk, bpk, hemb, hpp,
                                                           cbuf, hfin, d);
    }

    k_ln<<<dim3(B * T / 4), 256, 0, stream>>>(hfin, gamma, beta, hn);
    k_head<<<dim3(B * T / 64), 256, 0, stream>>>(hn, head_W, head_b, logits);
}

// Round 12
// 2868.219 us; speedup vs baseline: 2.5124x; 1.0942x over previous
//
#include <hip/hip_runtime.h>
#include <hip/hip_bf16.h>
#include <math.h>

// Problem constants
constexpr int B = 64, T = 128, D = 512, L = 9, S = 64;
constexpr int G = 4 * D;  // 2048 gate rows per layer

typedef __attribute__((ext_vector_type(8))) short short8;          // 8 bf16 = 4 VGPR
typedef __attribute__((ext_vector_type(8))) unsigned short ushort8;
typedef __attribute__((ext_vector_type(4))) float f32x4;

// ---------------------------------------------------------------------------
// Workspace layout (bytes):
//  Wpk  [L][2048][1024] bf16  rows remapped rr=4*d+gate; k<512=W_ih, k>=512=W_hh
//  bpk  [L][2048] f32         same row remap
//  hemb [T][B][D] bf16
//  hpp  [2][L][B][D] bf16     parity ping-pong h state (incl. layer 8)
//  hfin [T][B][D] f32         layer-8 h history (feeds LayerNorm)
//  cbuf [L*32][16][64] f32    c state, lane-private register-order layout
// ---------------------------------------------------------------------------
constexpr size_t WPK_BYTES  = (size_t)L * 2048 * 1024 * 2;   // 37,748,736
constexpr size_t BPK_BYTES  = (size_t)L * 2048 * 4;          // 73,728
constexpr size_t HEMB_BYTES = (size_t)T * B * D * 2;         // 8,388,608
constexpr size_t HPP_BYTES  = (size_t)2 * L * B * D * 2;     // 1,179,648
constexpr size_t HFIN_BYTES = (size_t)T * B * D * 4;         // 16,777,216

// ---------------------------------------------------------------------------
// K0: pack weights+bias to bf16, fused [ih|hh] K-space, remapped rows.
// ---------------------------------------------------------------------------
__global__ __launch_bounds__(256) void k_pack(const float* __restrict__ W_ih,
                                              const float* __restrict__ W_hh,
                                              const float* __restrict__ bsrc,
                                              unsigned short* __restrict__ Wpk,
                                              float* __restrict__ bpk) {
    int rr = blockIdx.x;
    int l  = rr >> 11;
    int rl = rr & 2047;
    int g  = rl & 3, dd = rl >> 2;
    int srow = g * D + dd;  // source row within layer (gate-major)
    int k = threadIdx.x * 4;
    const float* src = (k < D) ? (W_ih + ((size_t)l * G + srow) * D + k)
                               : (W_hh + ((size_t)l * G + srow) * D + (k - D));
    float4 v = *(const float4*)src;
    __hip_bfloat16 b0 = __float2bfloat16(v.x), b1 = __float2bfloat16(v.y),
                   b2 = __float2bfloat16(v.z), b3 = __float2bfloat16(v.w);
    ushort4 pk;
    pk.x = *(unsigned short*)&b0; pk.y = *(unsigned short*)&b1;
    pk.z = *(unsigned short*)&b2; pk.w = *(unsigned short*)&b3;
    *(ushort4*)(Wpk + ((size_t)l * 2048 + rl) * 1024 + k) = pk;
    if (threadIdx.x == 0) bpk[(size_t)l * 2048 + rl] = bsrc[(size_t)l * G + srow];
}

// ---------------------------------------------------------------------------
// K1: embedding gather -> hemb [t][b][d] bf16.
// ---------------------------------------------------------------------------
__global__ __launch_bounds__(256) void k_embed(const int* __restrict__ x,
                                               const float* __restrict__ emb,
                                               unsigned short* __restrict__ hemb) {
    int row = blockIdx.x * 2 + (threadIdx.x >> 7);  // row = t*B + b
    int t = row >> 6, b = row & 63;
    int d0 = (threadIdx.x & 127) * 4;
    int xi = x[b * T + t];
    float4 v = *(const float4*)(emb + (size_t)xi * D + d0);
    __hip_bfloat16 b0 = __float2bfloat16(v.x), b1 = __float2bfloat16(v.y),
                   b2 = __float2bfloat16(v.z), b3 = __float2bfloat16(v.w);
    ushort4 pk;
    pk.x = *(unsigned short*)&b0; pk.y = *(unsigned short*)&b1;
    pk.z = *(unsigned short*)&b2; pk.w = *(unsigned short*)&b3;
    *(ushort4*)(hemb + (size_t)row * D + d0) = pk;
}

// ---------------------------------------------------------------------------
// K2: one wavefront-diagonal of LSTM cells.
// One launch per diagonal d (= l + t); grid = ncells*32 ONE-WAVE blocks.
// Block = (cell ci, bt): output tile = 64 batches x 64 wrows.
//
// Inner loop:
//  - 4-deep LDS ring (W tile 8KB + h tile 8KB per step), fed by
//    global_load_lds width=16. Depth 4 (NOT 3): stage target (s+3)&3 is
//    always distinct from compute buffer s&3 -- the round-11 bug was ring
//    depth 3 overwriting the buffer being consumed (race).
//  - Single wave => NO barriers, only counted vmcnt. Baseline drained to 0
//    before the staging prologue so the counts are exact.
//  - Both tiles XOR-swizzled: linear LDS dest + inverse-permuted global
//    SOURCE chunk (rule #21), read back with chunk ^ (row&7) -> conflict-free
//    ds_read_b128.
//  - MFMA operand order (A=wf, B=hf) => acc[rt][wc].xyzw = gates i,f,g,o of
//    cell (dd = bt*16+wc*4+fq, bb = rt*16+fr): no cross-lane transpose.
//  - c state in global, lane-private register-order layout (coalesced).
// State ping-pong by diagonal parity: reads parity p^1, writes parity p.
// ---------------------------------------------------------------------------
__shared__ unsigned short Wt[4][64][64];  // 32 KB ring: [buf][wrow][k]
__shared__ unsigned short Ht[4][64][64];  // 32 KB ring: [buf][b][k]

__device__ __forceinline__ void wait_vm(int n) {
    if (n == 32)      asm volatile("s_waitcnt vmcnt(32)" ::: "memory");
    else if (n == 16) asm volatile("s_waitcnt vmcnt(16)" ::: "memory");
    else              asm volatile("s_waitcnt vmcnt(0)" ::: "memory");
}

__device__ __forceinline__ void stage_step(const unsigned short* __restrict__ hb,
                                           const unsigned short* __restrict__ hp,
                                           const unsigned short* __restrict__ wbase,
                                           int step, int buf, int lane) {
    const int k0  = step * 64;
    const int rl  = lane >> 3;              // row-in-8
    const int cc  = lane & 7;               // 16B chunk
    const int csw = ((cc ^ rl) & 7) << 3;   // inverse-swizzled element offset
    // W tile: 8 issues x (8 rows x 128B)
#pragma unroll
    for (int it = 0; it < 8; ++it) {
        const unsigned short* src = wbase + (size_t)(it * 8 + rl) * 1024 + k0 + csw;
        __builtin_amdgcn_global_load_lds(
            (const __attribute__((address_space(1))) unsigned int*)src,
            (__attribute__((address_space(3))) unsigned int*)&Wt[buf][it * 8][0],
            16, 0, 0);
    }
    // h tile
    const unsigned short* hx = (k0 < D) ? hb : hp;
    const int kk = (k0 & (D - 1)) + csw;
#pragma unroll
    for (int it = 0; it < 8; ++it) {
        const unsigned short* src = hx + (size_t)(it * 8 + rl) * D + kk;
        __builtin_amdgcn_global_load_lds(
            (const __attribute__((address_space(1))) unsigned int*)src,
            (__attribute__((address_space(3))) unsigned int*)&Ht[buf][it * 8][0],
            16, 0, 0);
    }
}

__device__ __forceinline__ void compute_step(f32x4 acc[4][4], int buf, int fr, int fq) {
#pragma unroll
    for (int kc = 0; kc < 2; kc++) {
#pragma unroll
        for (int wc = 0; wc < 4; wc++) {
            const int Rw = wc * 16 + fr;
            short8 wf = *(const short8*)&Wt[buf][Rw][(((kc * 4 + fq) ^ (Rw & 7)) << 3)];
#pragma unroll
            for (int rt = 0; rt < 4; rt++) {
                const int Rh = rt * 16 + fr;
                short8 hf = *(const short8*)&Ht[buf][Rh][(((kc * 4 + fq) ^ (Rh & 7)) << 3)];
                acc[rt][wc] = __builtin_amdgcn_mfma_f32_16x16x32_bf16(
                    wf, hf, acc[rt][wc], 0, 0, 0);
            }
        }
    }
}

template <int NS>
__device__ __forceinline__ void gemm_lds(f32x4 acc[4][4],
                                         const unsigned short* __restrict__ hb,
                                         const unsigned short* __restrict__ hp,
                                         const unsigned short* __restrict__ wbase,
                                         int lane, int fr, int fq) {
    stage_step(hb, hp, wbase, 0, 0, lane);
    stage_step(hb, hp, wbase, 1, 1, lane);
    stage_step(hb, hp, wbase, 2, 2, lane);
#pragma unroll
    for (int s = 0; s < NS; ++s) {
        wait_vm(s < NS - 2 ? 32 : (s == NS - 2 ? 16 : 0));
        if (s + 3 < NS) stage_step(hb, hp, wbase, s + 3, (s + 3) & 3, lane);
        compute_step(acc, s & 3, fr, fq);
    }
}

__global__ __launch_bounds__(64) void k_cell(const unsigned short* __restrict__ Wpk,
                                             const float* __restrict__ bpk,
                                             const unsigned short* __restrict__ hemb,
                                             unsigned short* __restrict__ hpp,
                                             float* __restrict__ cbuf,
                                             float* __restrict__ hfin,
                                             int d) {
    const int lmin = (d > T - 1) ? (d - (T - 1)) : 0;
    const int l  = lmin + (blockIdx.x >> 5);
    const int bt = blockIdx.x & 31;
    const int t  = d - l;
    const int p  = d & 1;

    const int lane = threadIdx.x;
    const int fr = lane & 15, fq = lane >> 4;

    const unsigned short* wbase = Wpk + ((size_t)l * 2048 + (size_t)bt * 64) * 1024;

    const unsigned short* hb = (l == 0)
        ? (hemb + (size_t)t * B * D)
        : (hpp + ((size_t)(p ^ 1) * L + (l - 1)) * B * D);
    const unsigned short* hp = hpp + ((size_t)(p ^ 1) * L + l) * B * D;
    unsigned short* hout = hpp + ((size_t)p * L + l) * B * D;

    // bias: dd = bt*16 + wc*4 + fq -> rows 4*dd..4*dd+3 (i,f,g,o)
    float4 bias4[4];
#pragma unroll
    for (int wc = 0; wc < 4; wc++)
        bias4[wc] = *(const float4*)(bpk + (size_t)l * 2048 + ((bt * 16 + wc * 4 + fq) << 2));
    // Drain VMEM queue so the counted vmcnt baseline in gemm_lds is exact
    // (bias4 loads would otherwise sit in the queue and shift the counts).
    asm volatile("s_waitcnt vmcnt(0)" ::: "memory");

    f32x4 acc[4][4];
#pragma unroll
    for (int i = 0; i < 4; i++)
#pragma unroll
        for (int j = 0; j < 4; j++) acc[i][j] = f32x4{0.f, 0.f, 0.f, 0.f};

    if (t > 0) gemm_lds<16>(acc, hb, hp, wbase, lane, fr, fq);
    else       gemm_lds<8>(acc, hb, hp, wbase, lane, fr, fq);

    __shared__ unsigned short hst[64][16];  // [batch][dd_local] bf16
    __shared__ float fst[64][16];           // f32 for hfin (l==8)

    // c: lane-private layout cbuf[(l*32+bt)*16 + rt*4+wc][lane]
    float* cb = cbuf + ((size_t)(l * 32 + bt) * 16) * 64 + lane;

#pragma unroll
    for (int rt = 0; rt < 4; rt++) {
#pragma unroll
        for (int wc = 0; wc < 4; wc++) {
            float gi = acc[rt][wc].x + bias4[wc].x;
            float gf = acc[rt][wc].y + bias4[wc].y;
            float gg = acc[rt][wc].z + bias4[wc].z;
            float go = acc[rt][wc].w + bias4[wc].w;
            float si = 1.f / (1.f + __expf(-gi));
            float sf = 1.f / (1.f + __expf(-gf));
            float so = 1.f / (1.f + __expf(-go));
            float tg = tanhf(gg);
            float co = (t > 0) ? cb[(rt * 4 + wc) * 64] : 0.f;
            float cn = fmaf(sf, co, si * tg);
            cb[(rt * 4 + wc) * 64] = cn;
            float hv = so * tanhf(cn);
            __hip_bfloat16 hvb = __float2bfloat16(hv);
            hst[rt * 16 + fr][wc * 4 + fq] = *(unsigned short*)&hvb;
            if (l == 8) fst[rt * 16 + fr][wc * 4 + fq] = hv;
        }
    }
    __syncthreads();
    // Coalesced store: lane = batch row, 16 dd values = 32 B
    {
        ushort8 r0 = *(const ushort8*)&hst[lane][0];
        ushort8 r1 = *(const ushort8*)&hst[lane][8];
        unsigned short* dst = hout + (size_t)lane * D + bt * 16;
        *(ushort8*)dst = r0;
        *(ushort8*)(dst + 8) = r1;
    }
    if (l == 8) {
        float* dst = hfin + ((size_t)t * B + lane) * D + bt * 16;
#pragma unroll
        for (int j = 0; j < 4; j++)
            *(float4*)(dst + j * 4) = *(const float4*)&fst[lane][j * 4];
    }
}

// ---------------------------------------------------------------------------
// K3: LayerNorm.  hfin [t*B+b][D] f32 -> hn [b*T+t][D] f32.  1 wave per row.
// ---------------------------------------------------------------------------
__global__ __launch_bounds__(256) void k_ln(const float* __restrict__ hfin,
                                            const float* __restrict__ gamma,
                                            const float* __restrict__ beta,
                                            float* __restrict__ hn) {
    int row  = blockIdx.x * 4 + (threadIdx.x >> 6);  // t*B + b
    int lane = threadIdx.x & 63;
    int t = row >> 6, b = row & 63;
    const float* in = hfin + (size_t)row * D;
    float4 a = *((const float4*)in + lane * 2);
    float4 c = *((const float4*)in + lane * 2 + 1);
    float s1 = a.x + a.y + a.z + a.w + c.x + c.y + c.z + c.w;
    float s2 = a.x * a.x + a.y * a.y + a.z * a.z + a.w * a.w +
               c.x * c.x + c.y * c.y + c.z * c.z + c.w * c.w;
#pragma unroll
    for (int m = 1; m < 64; m <<= 1) {
        s1 += __shfl_xor(s1, m);
        s2 += __shfl_xor(s2, m);
    }
    float mean = s1 / D;
    float rstd = rsqrtf(s2 / D - mean * mean + 1e-5f);
    float4 g0 = *((const float4*)gamma + lane * 2);
    float4 g1 = *((const float4*)gamma + lane * 2 + 1);
    float4 be0 = *((const float4*)beta + lane * 2);
    float4 be1 = *((const float4*)beta + lane * 2 + 1);
    float4 o0, o1;
    o0.x = fmaf((a.x - mean) * rstd, g0.x, be0.x);
    o0.y = fmaf((a.y - mean) * rstd, g0.y, be0.y);
    o0.z = fmaf((a.z - mean) * rstd, g0.z, be0.z);
    o0.w = fmaf((a.w - mean) * rstd, g0.w, be0.w);
    o1.x = fmaf((c.x - mean) * rstd, g1.x, be1.x);
    o1.y = fmaf((c.y - mean) * rstd, g1.y, be1.y);
    o1.z = fmaf((c.z - mean) * rstd, g1.z, be1.z);
    o1.w = fmaf((c.w - mean) * rstd, g1.w, be1.w);
    float* out = hn + ((size_t)b * T + t) * D;
    *((float4*)out + lane * 2) = o0;
    *((float4*)out + lane * 2 + 1) = o1;
}

// ---------------------------------------------------------------------------
// K4: head GEMM  logits[m][s] = sum_k hn[m][k]*head_W[s][k] + head_b[s]
// ---------------------------------------------------------------------------
__global__ __launch_bounds__(256) void k_head(const float* __restrict__ hn,
                                              const float* __restrict__ hw,
                                              const float* __restrict__ hb,
                                              float* __restrict__ out) {
    int m0 = blockIdx.x * 64;
    int tid = threadIdx.x;
    int tx = tid & 15, ty = tid >> 4;

    __shared__ float As[32][68];
    __shared__ float Bs[32][68];
    float acc[4][4] = {};

    for (int k0 = 0; k0 < D; k0 += 32) {
        int mm = tid >> 3, f4k = tid & 7;
#pragma unroll
        for (int h2 = 0; h2 < 2; h2++) {
            int m = mm + h2 * 32;
            float4 a = *((const float4*)(hn + (size_t)(m0 + m) * D + k0) + f4k);
            As[f4k * 4 + 0][m] = a.x;
            As[f4k * 4 + 1][m] = a.y;
            As[f4k * 4 + 2][m] = a.z;
            As[f4k * 4 + 3][m] = a.w;
            float4 wv = *((const float4*)(hw + (size_t)m * D + k0) + f4k);
            Bs[f4k * 4 + 0][m] = wv.x;
            Bs[f4k * 4 + 1][m] = wv.y;
            Bs[f4k * 4 + 2][m] = wv.z;
            Bs[f4k * 4 + 3][m] = wv.w;
        }
        __syncthreads();
#pragma unroll
        for (int k = 0; k < 32; k++) {
            float4 a  = *(float4*)&As[k][ty * 4];
            float4 bb = *(float4*)&Bs[k][tx * 4];
            float av[4] = {a.x, a.y, a.z, a.w};
            float bv[4] = {bb.x, bb.y, bb.z, bb.w};
#pragma unroll
            for (int i = 0; i < 4; i++)
#pragma unroll
                for (int j = 0; j < 4; j++) acc[i][j] = fmaf(av[i], bv[j], acc[i][j]);
        }
        __syncthreads();
    }
    float* o = out + (size_t)m0 * S;
#pragma unroll
    for (int i = 0; i < 4; i++) {
        int m = ty * 4 + i;
        float4 v;
        v.x = acc[i][0] + hb[tx * 4 + 0];
        v.y = acc[i][1] + hb[tx * 4 + 1];
        v.z = acc[i][2] + hb[tx * 4 + 2];
        v.w = acc[i][3] + hb[tx * 4 + 3];
        *(float4*)(o + (size_t)m * S + tx * 4) = v;
    }
}

// ---------------------------------------------------------------------------
extern "C" void kernel_launch(void* const* d_in, const int* in_sizes, int n_in,
                              void* d_out, int out_size, void* d_ws, size_t ws_size,
                              hipStream_t stream) {
    const int*   x      = (const int*)d_in[0];
    const float* emb    = (const float*)d_in[1];
    const float* W_ih   = (const float*)d_in[2];
    const float* W_hh   = (const float*)d_in[3];
    const float* bvec   = (const float*)d_in[4];
    const float* gamma  = (const float*)d_in[5];
    const float* beta   = (const float*)d_in[6];
    const float* head_W = (const float*)d_in[7];
    const float* head_b = (const float*)d_in[8];

    float* logits = (float*)d_out;                      // [B,T,S]
    float* hn     = (float*)d_out + (size_t)B * T * S;  // [B,T,D]

    char* ws = (char*)d_ws;
    unsigned short* Wpk  = (unsigned short*)ws;
    float*          bpk  = (float*)(ws + WPK_BYTES);
    unsigned short* hemb = (unsigned short*)(ws + WPK_BYTES + BPK_BYTES);
    unsigned short* hpp  = (unsigned short*)(ws + WPK_BYTES + BPK_BYTES + HEMB_BYTES);
    float*          hfin = (float*)(ws + WPK_BYTES + BPK_BYTES + HEMB_BYTES + HPP_BYTES);
    float*          cbuf = (float*)(ws + WPK_BYTES + BPK_BYTES + HEMB_BYTES + HPP_BYTES + HFIN_BYTES);

    k_pack<<<dim3(L * 2048), 256, 0, stream>>>(W_ih, W_hh, bvec, Wpk, bpk);
    k_embed<<<dim3(T * B / 2), 256, 0, stream>>>(x, emb, hemb);

    for (int d = 0; d < L + T - 1; ++d) {
        int lmin = (d > T - 1) ? (d - (T - 1)) : 0;
        int lmax = (d < L - 1) ? d : (L - 1);
        int ncells = lmax - lmin + 1;
        k_cell<<<dim3(ncells * 32), dim3(64), 0, stream>>>(Wpk, bpk, hemb, hpp,
                                                           cbuf, hfin, d);
    }

    k_ln<<<dim3(B * T / 4), 256, 0, stream>>>(hfin, gamma, beta, hn);
    k_head<<<dim3(B * T / 64), 256, 0, stream>>>(hn, head_W, head_b, logits);
}